// Round 8
// baseline (255.443 us; speedup 1.0000x reference)
//
#include <hip/hip_runtime.h>

using short8 = __attribute__((ext_vector_type(8))) short;
using f32x4  = __attribute__((ext_vector_type(4))) float;

constexpr int NN = 4096;   // seq len
constexpr int DD = 64;     // head dim
constexpr int MM = 512;    // sketch dim
constexpr int BH = 64;     // B*H

// float -> bf16 (RNE)
__device__ __forceinline__ short f2bf(float f) {
    union { float f; unsigned u; } v; v.f = f;
    unsigned r = v.u + 0x7FFF + ((v.u >> 16) & 1);
    return (short)(r >> 16);
}

// pack two f32 -> one u32 of 2 bf16 (lo = first arg). No builtin on gfx950.
__device__ __forceinline__ unsigned cvt_pk_bf16(float lo, float hi) {
    unsigned r;
    asm("v_cvt_pk_bf16_f32 %0, %1, %2" : "=v"(r) : "v"(lo), "v"(hi));
    return r;
}

// ---------------------------------------------------------------------------
// Sketch kernel: builds sks[bh][m][d] (natural m order) and stvT[bh][d][m]
// with m PERMUTED within each 64-chunk: column bits [m5..m0]->[m4 m3 m2 m5 m1 m0].
// This makes swapped-GEMM1's register-resident P land exactly on GEMM2's
// A-fragment slots in the attention kernel (no LDS round trip for P).
// ---------------------------------------------------------------------------
__global__ __launch_bounds__(1024) void sketch_kernel(
    const float* __restrict__ K, const float* __restrict__ V,
    short* __restrict__ sks, short* __restrict__ stvT) {
    __shared__ float lds[64][65];
    const int t  = threadIdx.x;
    const int lo = t & 63;
    const int hi = t >> 6;      // 0..15
    const int bh = blockIdx.x >> 3;
    const int g  = blockIdx.x & 7;
    const float* Kb = K + ((size_t)bh * NN + g * 512) * DD;
    const float* Vb = V + ((size_t)bh * NN + g * 512) * DD;

#pragma unroll
    for (int i = 0; i < 4; ++i) {
        int e = hi * 4 + i;
        float s = 0.f;
#pragma unroll
        for (int c = 0; c < 8; ++c)
            s += Kb[(size_t)(c * 64 + e) * DD + lo];   // lane = d, coalesced
        lds[e][lo] = s * 0.125f;
    }
    __syncthreads();
#pragma unroll
    for (int i = 0; i < 4; ++i) {
        int d = hi * 4 + i;
        sks[((size_t)bh * MM + d * 8 + g) * DD + lo] = f2bf(lds[lo][d]);
    }
    __syncthreads();
#pragma unroll
    for (int i = 0; i < 4; ++i) {
        int ml = hi * 4 + i;
        float s = 0.f;
#pragma unroll
        for (int c = 0; c < 8; ++c)
            s += Vb[(size_t)(ml * 8 + c) * DD + lo];   // lane = e, coalesced
        lds[ml][lo] = s * 0.125f;
    }
    __syncthreads();
    // m-permutation within the 64-chunk (within 128B window: still coalesced)
    const int pm = ((lo & 0x1C) << 1) | ((lo & 0x20) >> 3) | (lo & 3);
#pragma unroll
    for (int i = 0; i < 4; ++i) {
        int e = hi * 4 + i;
        stvT[((size_t)bh * DD + e) * MM + g * 64 + pm] = f2bf(lds[lo][e]);
    }
}

// ---------------------------------------------------------------------------
// Attention kernel v8: ALL-RESIDENT LDS. The entire per-bh operand set
// (sks 64 KB + stv 64 KB -> 144 KB padded) is staged into LDS once, then the
// 8-chunk loop runs with ZERO barriers: waves free-run at different phases
// (MFMA/VALU/LDS pipes fill concurrently) and the compiler pipelines
// GEMM1(mc+1) under exp/GEMM2(mc). 512 threads = 8 waves x 64 rows; grid
// 512 blocks (1/CU, 2 rounds). Swapped GEMM1 + in-register P as before.
// ---------------------------------------------------------------------------
__global__ __launch_bounds__(512, 2) void attn_kernel(
    const float* __restrict__ Q, const float* __restrict__ V,
    const short* __restrict__ sks, const short* __restrict__ stvT,
    float* __restrict__ out) {
    __shared__ __align__(16) short sks_s[8][64][72];    // [chunk][m-local][d], +8 pad
    __shared__ __align__(16) short stv_s[8][64][72];    // [chunk][d][m-local(perm)]

    const int tid  = threadIdx.x;
    const int wave = tid >> 6;
    const int lane = tid & 63;
    const int quad = lane >> 4;
    const int l16  = lane & 15;
    const int bh   = blockIdx.x >> 3;                   // 64 bh x 8 blocks
    const int rb   = (blockIdx.x & 7) * 512 + wave * 64;

    const short* sksb = sks + (size_t)bh * MM * DD;
    const short* stvb = stvT + (size_t)bh * DD * MM;

    // --- stage ALL 8 chunks (one-shot), fully coalesced 16B/lane ---
    {
        const int srow = tid >> 3;            // 0..63
        const int scol = (tid & 7) * 8;       // 0..56
#pragma unroll
        for (int mc = 0; mc < 8; ++mc) {
            const short* gk = sksb + (size_t)(mc * 64 + srow) * DD + scol;
            const short* gv = stvb + (size_t)srow * MM + mc * 64 + scol;
            *(short8*)&sks_s[mc][srow][scol] = *(const short8*)gk;
            *(short8*)&stv_s[mc][srow][scol] = *(const short8*)gv;
        }
    }

    // Q fragments (MFMA B operand in swapped GEMM1), pre-scaled 1/8
    short8 aq[4][2];
#pragma unroll
    for (int t = 0; t < 4; ++t) {
        const float* qr = Q + ((size_t)bh * NN + rb + t * 16 + l16) * DD;
#pragma unroll
        for (int kc = 0; kc < 2; ++kc) {
            f32x4 f0 = *(const f32x4*)&qr[kc * 32 + quad * 8];
            f32x4 f1 = *(const f32x4*)&qr[kc * 32 + quad * 8 + 4];
#pragma unroll
            for (int j = 0; j < 4; ++j) {
                aq[t][kc][j]     = f2bf(f0[j] * 0.125f);
                aq[t][kc][j + 4] = f2bf(f1[j] * 0.125f);
            }
        }
    }

    f32x4 O[4][4];
#pragma unroll
    for (int t = 0; t < 4; ++t)
#pragma unroll
        for (int nb = 0; nb < 4; ++nb) O[t][nb] = (f32x4){0.f, 0.f, 0.f, 0.f};
    float psum[4] = {0.f, 0.f, 0.f, 0.f};

    __syncthreads();                           // the ONLY barrier

#pragma unroll 2
    for (int mc = 0; mc < 8; ++mc) {
        // --- GEMM1 (swapped): S^T = mfma(SKS, Q); lane holds q = l16,
        //     m = jb*16 + quad*4 + r. am fragments shared by all 4 tiles. ---
        unsigned pk[4][4][2];
#pragma unroll
        for (int jb = 0; jb < 4; ++jb) {
            f32x4 s[4];
#pragma unroll
            for (int t = 0; t < 4; ++t) s[t] = (f32x4){0.f, 0.f, 0.f, 0.f};
#pragma unroll
            for (int kc = 0; kc < 2; ++kc) {
                short8 am = *(const short8*)&sks_s[mc][jb * 16 + l16][kc * 32 + quad * 8];
#pragma unroll
                for (int t = 0; t < 4; ++t)
                    s[t] = __builtin_amdgcn_mfma_f32_16x16x32_bf16(am, aq[t][kc], s[t], 0, 0, 0);
            }
#pragma unroll
            for (int t = 0; t < 4; ++t)
#pragma unroll
                for (int rp = 0; rp < 2; ++rp) {
                    float e0 = __expf(s[t][2 * rp]), e1 = __expf(s[t][2 * rp + 1]);
                    psum[t] += e0 + e1;
                    pk[t][jb][rp] = cvt_pk_bf16(e0, e1);
                }
        }

        // --- assemble GEMM2 A-fragments from registers (slot map: kc = jb&1,
        //     j = (jb>>1)*4 + r; STV permutation makes this consistent) ---
        short8 ap[4][2];
#pragma unroll
        for (int t = 0; t < 4; ++t) {
            union { unsigned u[4]; short8 s; } u0, u1;
            u0.u[0] = pk[t][0][0]; u0.u[1] = pk[t][0][1];
            u0.u[2] = pk[t][2][0]; u0.u[3] = pk[t][2][1];
            u1.u[0] = pk[t][1][0]; u1.u[1] = pk[t][1][1];
            u1.u[2] = pk[t][3][0]; u1.u[3] = pk[t][3][1];
            ap[t][0] = u0.s; ap[t][1] = u1.s;
        }

        // --- GEMM2: O += P_chunk @ STV_chunk (A from regs; b shared by tiles) ---
#pragma unroll
        for (int kc = 0; kc < 2; ++kc)
#pragma unroll
            for (int nb = 0; nb < 4; ++nb) {
                short8 b = *(const short8*)&stv_s[mc][nb * 16 + l16][kc * 32 + quad * 8];
#pragma unroll
                for (int t = 0; t < 4; ++t)
                    O[t][nb] = __builtin_amdgcn_mfma_f32_16x16x32_bf16(ap[t][kc], b, O[t][nb], 0, 0, 0);
            }
    }

    // --- normalize + fused +V epilogue ---
    // psum[t] at lane (quad,l16) covers m in its quad-slice; reduce over quads.
    float inv[4];
#pragma unroll
    for (int t = 0; t < 4; ++t) {
        float s = psum[t];
        s += __shfl_xor(s, 16);
        s += __shfl_xor(s, 32);
        inv[t] = 1.0f / s;                 // denominator for q-row = l16
    }
#pragma unroll
    for (int t = 0; t < 4; ++t)
#pragma unroll
        for (int r = 0; r < 4; ++r) {
            float iv = __shfl(inv[t], quad * 4 + r);   // lane l16==q holds it
#pragma unroll
            for (int nb = 0; nb < 4; ++nb) {
                size_t idx = ((size_t)bh * NN + rb + t * 16 + quad * 4 + r) * DD + nb * 16 + l16;
                out[idx] = O[t][nb][r] * iv + V[idx];
            }
        }
}

extern "C" void kernel_launch(void* const* d_in, const int* in_sizes, int n_in,
                              void* d_out, int out_size, void* d_ws, size_t ws_size,
                              hipStream_t stream) {
    const float* Q = (const float*)d_in[0];
    const float* K = (const float*)d_in[1];
    const float* V = (const float*)d_in[2];
    float* out = (float*)d_out;

    short* sks  = (short*)d_ws;                  // BH*MM*DD bf16 = 4 MB
    short* stvT = sks + (size_t)BH * MM * DD;    // BH*DD*MM bf16 = 4 MB

    sketch_kernel<<<BH * 8, 1024, 0, stream>>>(K, V, sks, stvT);
    attn_kernel<<<BH * (NN / 512), 512, 0, stream>>>(Q, V, sks, stvT, out);
}

// Round 10
// 244.673 us; speedup vs baseline: 1.0440x; 1.0440x over previous
//
#include <hip/hip_runtime.h>

using short8 = __attribute__((ext_vector_type(8))) short;
using f32x4  = __attribute__((ext_vector_type(4))) float;

constexpr int NN = 4096;   // seq len
constexpr int DD = 64;     // head dim
constexpr int MM = 512;    // sketch dim
constexpr int BH = 64;     // B*H

// float -> bf16 (RNE)
__device__ __forceinline__ short f2bf(float f) {
    union { float f; unsigned u; } v; v.f = f;
    unsigned r = v.u + 0x7FFF + ((v.u >> 16) & 1);
    return (short)(r >> 16);
}

// pack two f32 -> one u32 of 2 bf16 (lo = first arg). No builtin on gfx950.
__device__ __forceinline__ unsigned cvt_pk_bf16(float lo, float hi) {
    unsigned r;
    asm("v_cvt_pk_bf16_f32 %0, %1, %2" : "=v"(r) : "v"(lo), "v"(hi));
    return r;
}

// ---------------------------------------------------------------------------
// Sketch kernel v2: same outputs as before (sks[bh][m][d]; stvT[bh][d][m]
// with the in-chunk m-permutation [m5..m0]->[m4 m3 m2 m5 m1 m0]), but the
// global c-sum loops now use float4 loads (8 x dwordx4 per thread instead of
// 32 x dword). LDS-transpose write-out phases unchanged.
// ---------------------------------------------------------------------------
__global__ __launch_bounds__(1024) void sketch_kernel(
    const float* __restrict__ K, const float* __restrict__ V,
    short* __restrict__ sks, short* __restrict__ stvT) {
    __shared__ float lds[64][65];
    const int t  = threadIdx.x;
    const int lo = t & 63;
    const int hi = t >> 6;      // 0..15
    const int bh = blockIdx.x >> 3;
    const int g  = blockIdx.x & 7;
    const float* Kb = K + ((size_t)bh * NN + g * 512) * DD;
    const float* Vb = V + ((size_t)bh * NN + g * 512) * DD;

    // --- K-phase: SKS[m=d*8+g][e] = mean_c K[g*512 + c*64 + e][d] ---
    // thread covers (row e = t>>4, cols d4..d4+3); lanes 0..63 read a
    // contiguous 1 KiB window (4 rows x 256 B) per c -> fully coalesced.
    {
        const int e  = t >> 4;
        const int d4 = (t & 15) * 4;
        f32x4 acc = (f32x4){0.f, 0.f, 0.f, 0.f};
#pragma unroll
        for (int c = 0; c < 8; ++c)
            acc += *(const f32x4*)&Kb[(size_t)(c * 64 + e) * DD + d4];
#pragma unroll
        for (int j = 0; j < 4; ++j)
            lds[e][d4 + j] = acc[j] * 0.125f;
    }
    __syncthreads();
#pragma unroll
    for (int i = 0; i < 4; ++i) {
        int d = hi * 4 + i;
        sks[((size_t)bh * MM + d * 8 + g) * DD + lo] = f2bf(lds[lo][d]);   // lane = e, coalesced
    }
    __syncthreads();

    // --- V-phase: STV[m][e] = mean_c V[m*8+c][e]; thread covers
    // (m2 = t>>4, cols e4..e4+3); 16 lanes cover a contiguous row segment.
    {
        const int m2 = t >> 4;
        const int e4 = (t & 15) * 4;
        f32x4 acc = (f32x4){0.f, 0.f, 0.f, 0.f};
#pragma unroll
        for (int c = 0; c < 8; ++c)
            acc += *(const f32x4*)&Vb[(size_t)(m2 * 8 + c) * DD + e4];
#pragma unroll
        for (int j = 0; j < 4; ++j)
            lds[m2][e4 + j] = acc[j] * 0.125f;
    }
    __syncthreads();
    // m-permutation within the 64-chunk (within 128B window: still coalesced)
    const int pm = ((lo & 0x1C) << 1) | ((lo & 0x20) >> 3) | (lo & 3);
#pragma unroll
    for (int i = 0; i < 4; ++i) {
        int e = hi * 4 + i;
        stvT[((size_t)bh * DD + e) * MM + g * 64 + pm] = f2bf(lds[lo][e]);
    }
}

// ---------------------------------------------------------------------------
// Attention kernel v7b (verified 66.4 us): 64 rows/wave (4 row-tiles of 16),
// 256 rows/block, grid 1024. LDS fragment reads are wave-invariant (am shared
// across tiles in swapped GEMM1; b shared across tiles in GEMM2), so halving
// wave count halves the LDS pipe load while doubling per-wave MFMA/VALU ILP.
// Double-buffered staging, one barrier per chunk. launch_bounds(256,2).
// ---------------------------------------------------------------------------
__global__ __launch_bounds__(256, 2) void attn_kernel(
    const float* __restrict__ Q, const float* __restrict__ V,
    const short* __restrict__ sks, const short* __restrict__ stvT,
    float* __restrict__ out) {
    __shared__ __align__(16) short sks_s[2][64][72];    // [buf][m-local][d], +8 pad
    __shared__ __align__(16) short stv_s[2][64][72];    // [buf][d][m-local(perm)]

    const int tid  = threadIdx.x;
    const int wave = tid >> 6;
    const int lane = tid & 63;
    const int quad = lane >> 4;
    const int l16  = lane & 15;
    const int bh   = blockIdx.x >> 4;                   // 64 bh x 16 blocks
    const int rb   = (blockIdx.x & 15) * 256 + wave * 64;

    const short* sksb = sks + (size_t)bh * MM * DD;
    const short* stvb = stvT + (size_t)bh * DD * MM;

    // Q fragments (MFMA B operand in swapped GEMM1), pre-scaled 1/8
    short8 aq[4][2];
#pragma unroll
    for (int t = 0; t < 4; ++t) {
        const float* qr = Q + ((size_t)bh * NN + rb + t * 16 + l16) * DD;
#pragma unroll
        for (int kc = 0; kc < 2; ++kc) {
            f32x4 f0 = *(const f32x4*)&qr[kc * 32 + quad * 8];
            f32x4 f1 = *(const f32x4*)&qr[kc * 32 + quad * 8 + 4];
#pragma unroll
            for (int j = 0; j < 4; ++j) {
                aq[t][kc][j]     = f2bf(f0[j] * 0.125f);
                aq[t][kc][j + 4] = f2bf(f1[j] * 0.125f);
            }
        }
    }

    f32x4 O[4][4];
#pragma unroll
    for (int t = 0; t < 4; ++t)
#pragma unroll
        for (int nb = 0; nb < 4; ++nb) O[t][nb] = (f32x4){0.f, 0.f, 0.f, 0.f};
    float psum[4] = {0.f, 0.f, 0.f, 0.f};

    // staging: thread covers 16 consecutive shorts of each 64x64 chunk
    const int srow = tid >> 2;            // 0..63
    const int scol = (tid & 3) * 16;      // 0,16,32,48
    short8 pfk0, pfk1, pfv0, pfv1;

    // prologue: chunk 0 -> buf 0, then prefetch chunk 1 into regs
    {
        const short* gk = sksb + (size_t)srow * DD + scol;
        const short* gv = stvb + (size_t)srow * MM + scol;
        pfk0 = *(const short8*)gk;  pfk1 = *(const short8*)(gk + 8);
        pfv0 = *(const short8*)gv;  pfv1 = *(const short8*)(gv + 8);
        *(short8*)&sks_s[0][srow][scol]     = pfk0;
        *(short8*)&sks_s[0][srow][scol + 8] = pfk1;
        *(short8*)&stv_s[0][srow][scol]     = pfv0;
        *(short8*)&stv_s[0][srow][scol + 8] = pfv1;
        const short* gk1 = sksb + (size_t)64 * DD + (size_t)srow * DD + scol;
        const short* gv1 = stvb + (size_t)srow * MM + 64 + scol;
        pfk0 = *(const short8*)gk1; pfk1 = *(const short8*)(gk1 + 8);
        pfv0 = *(const short8*)gv1; pfv1 = *(const short8*)(gv1 + 8);
    }
    __syncthreads();

    for (int mc = 0; mc < 8; ++mc) {
        const int p = mc & 1;
        if (mc < 7) {                      // write chunk mc+1 into other buffer
            *(short8*)&sks_s[p ^ 1][srow][scol]     = pfk0;
            *(short8*)&sks_s[p ^ 1][srow][scol + 8] = pfk1;
            *(short8*)&stv_s[p ^ 1][srow][scol]     = pfv0;
            *(short8*)&stv_s[p ^ 1][srow][scol + 8] = pfv1;
        }
        if (mc < 6) {                      // issue loads for chunk mc+2
            const short* gk = sksb + (size_t)(mc + 2) * 64 * DD + (size_t)srow * DD + scol;
            const short* gv = stvb + (size_t)srow * MM + (mc + 2) * 64 + scol;
            pfk0 = *(const short8*)gk;  pfk1 = *(const short8*)(gk + 8);
            pfv0 = *(const short8*)gv;  pfv1 = *(const short8*)(gv + 8);
        }

        // --- GEMM1 (swapped): S^T = mfma(SKS, Q); lane holds q = l16,
        //     m = jb*16 + quad*4 + r. am fragments shared by all 4 tiles. ---
        unsigned pk[4][4][2];
#pragma unroll
        for (int jb = 0; jb < 4; ++jb) {
            f32x4 s[4];
#pragma unroll
            for (int t = 0; t < 4; ++t) s[t] = (f32x4){0.f, 0.f, 0.f, 0.f};
#pragma unroll
            for (int kc = 0; kc < 2; ++kc) {
                short8 am = *(const short8*)&sks_s[p][jb * 16 + l16][kc * 32 + quad * 8];
#pragma unroll
                for (int t = 0; t < 4; ++t)
                    s[t] = __builtin_amdgcn_mfma_f32_16x16x32_bf16(am, aq[t][kc], s[t], 0, 0, 0);
            }
#pragma unroll
            for (int t = 0; t < 4; ++t)
#pragma unroll
                for (int rp = 0; rp < 2; ++rp) {
                    float e0 = __expf(s[t][2 * rp]), e1 = __expf(s[t][2 * rp + 1]);
                    psum[t] += e0 + e1;
                    pk[t][jb][rp] = cvt_pk_bf16(e0, e1);
                }
        }

        // --- assemble GEMM2 A-fragments from registers (slot map: kc = jb&1,
        //     j = (jb>>1)*4 + r; STV permutation makes this consistent) ---
        short8 ap[4][2];
#pragma unroll
        for (int t = 0; t < 4; ++t) {
            union { unsigned u[4]; short8 s; } u0, u1;
            u0.u[0] = pk[t][0][0]; u0.u[1] = pk[t][0][1];
            u0.u[2] = pk[t][2][0]; u0.u[3] = pk[t][2][1];
            u1.u[0] = pk[t][1][0]; u1.u[1] = pk[t][1][1];
            u1.u[2] = pk[t][3][0]; u1.u[3] = pk[t][3][1];
            ap[t][0] = u0.s; ap[t][1] = u1.s;
        }

        // --- GEMM2: O += P_chunk @ STV_chunk (A from regs; b shared by tiles) ---
#pragma unroll
        for (int kc = 0; kc < 2; ++kc)
#pragma unroll
            for (int nb = 0; nb < 4; ++nb) {
                short8 b = *(const short8*)&stv_s[p][nb * 16 + l16][kc * 32 + quad * 8];
#pragma unroll
                for (int t = 0; t < 4; ++t)
                    O[t][nb] = __builtin_amdgcn_mfma_f32_16x16x32_bf16(ap[t][kc], b, O[t][nb], 0, 0, 0);
            }

        __syncthreads();                   // single barrier per chunk
    }

    // --- normalize + fused +V epilogue ---
    // psum[t] at lane (quad,l16) covers m in its quad-slice; reduce over quads.
    float inv[4];
#pragma unroll
    for (int t = 0; t < 4; ++t) {
        float s = psum[t];
        s += __shfl_xor(s, 16);
        s += __shfl_xor(s, 32);
        inv[t] = 1.0f / s;                 // denominator for q-row = l16
    }
#pragma unroll
    for (int t = 0; t < 4; ++t)
#pragma unroll
        for (int r = 0; r < 4; ++r) {
            float iv = __shfl(inv[t], quad * 4 + r);   // lane l16==q holds it
#pragma unroll
            for (int nb = 0; nb < 4; ++nb) {
                size_t idx = ((size_t)bh * NN + rb + t * 16 + quad * 4 + r) * DD + nb * 16 + l16;
                out[idx] = O[t][nb][r] * iv + V[idx];
            }
        }
}

extern "C" void kernel_launch(void* const* d_in, const int* in_sizes, int n_in,
                              void* d_out, int out_size, void* d_ws, size_t ws_size,
                              hipStream_t stream) {
    const float* Q = (const float*)d_in[0];
    const float* K = (const float*)d_in[1];
    const float* V = (const float*)d_in[2];
    float* out = (float*)d_out;

    short* sks  = (short*)d_ws;                  // BH*MM*DD bf16 = 4 MB
    short* stvT = sks + (size_t)BH * MM * DD;    // BH*DD*MM bf16 = 4 MB

    sketch_kernel<<<BH * 8, 1024, 0, stream>>>(K, V, sks, stvT);
    attn_kernel<<<BH * (NN / 256), 256, 0, stream>>>(Q, V, sks, stvT, out);
}